// Round 1
// baseline (729.665 us; speedup 1.0000x reference)
//
#include <hip/hip_runtime.h>

// SelfAttention block, algebraically restructured:
//   xn = GN(x) = x*sc[b,c] + sh[b,c]
//   G[b] = xn @ xn^T                       (256x256, K=4096)  -- only heavy read of x
//   logits = (Wq G Wk^T + bias corr)*scale  (small 256^3 GEMMs per batch)
//   attn = softmax(logits)
//   S[b] = Pw @ attn @ Wv                  (small)
//   out = x + S[b] @ xn + const[b,o]       (K=256 GEMM fused with residual)

#define B_ 32
#define C_ 256
#define N_ 4096
#define CPG 32
#define GSIZE (CPG * N_)
#define EPSV 1e-5f
#define SCALE 0.0625f

// workspace layout (floats)
#define OFF_SC    0
#define OFF_SH    8192
#define OFF_SVEC  16384
#define OFF_RALL  24576
#define OFF_CV    49152
#define OFF_CONST 57344
#define OFF_GM    65536
#define OFF_T1    (OFF_GM + 2097152)
#define OFF_L     (OFF_T1 + 2097152)
#define OFF_T2    (OFF_L + 2097152)
#define OFF_S     (OFF_T2 + 2097152)

// ---------------- GroupNorm stats: mean/rstd per (b,g) + per-channel sums ----
__global__ __launch_bounds__(256) void gn_stats_k(
    const float* __restrict__ x, const float* __restrict__ gw,
    const float* __restrict__ gb, float* __restrict__ ws) {
  int blk = blockIdx.x, b = blk >> 3, g = blk & 7;
  int t = threadIdx.x, lane = t & 63, wid = t >> 6;
  __shared__ float wsum[4], wsq[4], chs[32], stats[2];
  float gs = 0.f, gq = 0.f;  // thread 0 accumulates group totals
  const float4* xg = (const float4*)(x + ((size_t)(b * C_) + g * CPG) * N_);
  for (int cc = 0; cc < CPG; ++cc) {
    const float4* p = xg + cc * (N_ / 4);
    float s = 0.f, q = 0.f;
#pragma unroll
    for (int j = 0; j < 4; ++j) {
      float4 v = p[t + j * 256];
      s += v.x + v.y + v.z + v.w;
      q += v.x * v.x + v.y * v.y + v.z * v.z + v.w * v.w;
    }
#pragma unroll
    for (int off = 32; off > 0; off >>= 1) {
      s += __shfl_down(s, off);
      q += __shfl_down(q, off);
    }
    if (lane == 0) { wsum[wid] = s; wsq[wid] = q; }
    __syncthreads();
    if (t == 0) {
      float cs = wsum[0] + wsum[1] + wsum[2] + wsum[3];
      float cq = wsq[0] + wsq[1] + wsq[2] + wsq[3];
      chs[cc] = cs; gs += cs; gq += cq;
    }
    __syncthreads();
  }
  if (t == 0) {
    float mean = gs * (1.f / GSIZE);
    float var = gq * (1.f / GSIZE) - mean * mean;
    stats[0] = mean;
    stats[1] = rsqrtf(var + EPSV);
  }
  __syncthreads();
  if (t < CPG) {
    int c = g * CPG + t, gi = b * C_ + c;
    float scv = stats[1] * gw[c];
    float shv = gb[c] - stats[0] * scv;
    ws[OFF_SC + gi] = scv;
    ws[OFF_SH + gi] = shv;
    ws[OFF_SVEC + gi] = chs[t] * scv + (float)N_ * shv;  // sum_n xn[c,n]
  }
}

// ---------------- r_all[b,o] = (Wqkv @ svec)[o], o in [0,768) ----------------
__global__ __launch_bounds__(256) void rall_k(const float* __restrict__ qkvw,
                                              float* __restrict__ ws) {
  int b = blockIdx.x, t = threadIdx.x;
  __shared__ float s[256];
  s[t] = ws[OFF_SVEC + b * C_ + t];
  __syncthreads();
  for (int oo = 0; oo < 3; ++oo) {
    int o = t + oo * 256;
    const float* w = qkvw + (size_t)o * C_;
    float acc = 0.f;
#pragma unroll 8
    for (int c = 0; c < C_; ++c) acc += w[c] * s[c];
    ws[OFF_RALL + b * 768 + o] = acc;
  }
}

// ---------------- Gram: G[b] = xn @ xn^T (M=N=256, K=4096) ------------------
__global__ __launch_bounds__(256) void gram_k(const float* __restrict__ x,
                                              float* __restrict__ ws) {
  int b = blockIdx.y;
  int mt = blockIdx.x >> 2, nt = blockIdx.x & 3;
  int c0 = mt * 64, d0 = nt * 64;
  int t = threadIdx.x, tx = t & 15, ty = t >> 4;
  __shared__ __align__(16) float As[32][68], Bs[32][68];
  const float* xb = x + (size_t)b * C_ * N_;
  const float* sc = ws + OFF_SC + b * C_;
  const float* sh = ws + OFF_SH + b * C_;
  float scA[8], shA[8], scB[8], shB[8];
  int mbase = t >> 5, kload = t & 31;
#pragma unroll
  for (int i = 0; i < 8; ++i) {
    int m = mbase + i * 8;
    scA[i] = sc[c0 + m]; shA[i] = sh[c0 + m];
    scB[i] = sc[d0 + m]; shB[i] = sh[d0 + m];
  }
  float acc[4][4] = {};
  for (int k0 = 0; k0 < N_; k0 += 32) {
#pragma unroll
    for (int i = 0; i < 8; ++i) {
      int m = mbase + i * 8;
      float av = xb[(size_t)(c0 + m) * N_ + k0 + kload];
      float bv = xb[(size_t)(d0 + m) * N_ + k0 + kload];
      As[kload][m] = av * scA[i] + shA[i];
      Bs[kload][m] = bv * scB[i] + shB[i];
    }
    __syncthreads();
#pragma unroll
    for (int kk = 0; kk < 32; ++kk) {
      const float4 a = *(const float4*)&As[kk][ty * 4];
      const float4 bb = *(const float4*)&Bs[kk][tx * 4];
      const float ar[4] = {a.x, a.y, a.z, a.w};
      const float br[4] = {bb.x, bb.y, bb.z, bb.w};
#pragma unroll
      for (int r = 0; r < 4; ++r)
#pragma unroll
        for (int s = 0; s < 4; ++s) acc[r][s] = fmaf(ar[r], br[s], acc[r][s]);
    }
    __syncthreads();
  }
  float* Gm = ws + OFF_GM + (size_t)b * 65536;
#pragma unroll
  for (int r = 0; r < 4; ++r) {
    float4 v = {acc[r][0], acc[r][1], acc[r][2], acc[r][3]};
    *(float4*)&Gm[(c0 + ty * 4 + r) * C_ + d0 + tx * 4] = v;
  }
}

// ---------------- small GEMM 256x256x256 per batch --------------------------
template <bool BTRANS, bool LOGITS>
__global__ __launch_bounds__(256) void sgemm256_k(
    const float* __restrict__ A, size_t aBS, const float* __restrict__ Bm,
    size_t bBS, float* __restrict__ Cm, const float* __restrict__ rall,
    const float* __restrict__ qkvb) {
  int b = blockIdx.y;
  int mt = blockIdx.x >> 2, nt = blockIdx.x & 3;
  int m0 = mt * 64, j0 = nt * 64;
  int t = threadIdx.x, tx = t & 15, ty = t >> 4;
  __shared__ __align__(16) float As[32][68], Bs[32][68];
  const float* Ab = A + aBS * b;
  const float* Bb = Bm + bBS * b;
  float acc[4][4] = {};
  for (int k0 = 0; k0 < 256; k0 += 32) {
    {
      int k = t & 31, m = t >> 5;
#pragma unroll
      for (int i = 0; i < 8; ++i)
        As[k][m + i * 8] = Ab[(m0 + m + i * 8) * 256 + k0 + k];
    }
    if (!BTRANS) {
      int j = t & 63, k = t >> 6;
#pragma unroll
      for (int i = 0; i < 8; ++i)
        Bs[k + i * 4][j] = Bb[(k0 + k + i * 4) * 256 + j0 + j];
    } else {
      int k = t & 31, j = t >> 5;
#pragma unroll
      for (int i = 0; i < 8; ++i)
        Bs[k][j + i * 8] = Bb[(j0 + j + i * 8) * 256 + k0 + k];
    }
    __syncthreads();
#pragma unroll
    for (int kk = 0; kk < 32; ++kk) {
      const float4 a = *(const float4*)&As[kk][ty * 4];
      const float4 bb = *(const float4*)&Bs[kk][tx * 4];
      const float ar[4] = {a.x, a.y, a.z, a.w};
      const float br[4] = {bb.x, bb.y, bb.z, bb.w};
#pragma unroll
      for (int r = 0; r < 4; ++r)
#pragma unroll
        for (int s = 0; s < 4; ++s) acc[r][s] = fmaf(ar[r], br[s], acc[r][s]);
    }
    __syncthreads();
  }
#pragma unroll
  for (int r = 0; r < 4; ++r) {
    int i = m0 + ty * 4 + r;
#pragma unroll
    for (int s = 0; s < 4; ++s) {
      int j = j0 + tx * 4 + s;
      float v = acc[r][s];
      if (LOGITS) {
        float bq = qkvb[i], bk = qkvb[256 + j];
        float rq = rall[b * 768 + i], rk = rall[b * 768 + 256 + j];
        v = (v + bq * rk + bk * rq + 4096.f * bq * bk) * SCALE;
      }
      Cm[(size_t)b * 65536 + i * 256 + j] = v;
    }
  }
}

// ---------------- softmax over rows of logits (in place) + cv ---------------
__global__ __launch_bounds__(256) void softmax_k(float* __restrict__ ws,
                                                 const float* __restrict__ qkvb) {
  int row = blockIdx.x;  // b*256 + c
  int t = threadIdx.x;
  __shared__ float red[256];
  float* L = ws + OFF_L + (size_t)row * 256;
  float v = L[t];
  red[t] = v;
  __syncthreads();
  for (int s = 128; s > 0; s >>= 1) {
    if (t < s) red[t] = fmaxf(red[t], red[t + s]);
    __syncthreads();
  }
  float m = red[0];
  __syncthreads();
  float e = __expf(v - m);
  red[t] = e;
  __syncthreads();
  for (int s = 128; s > 0; s >>= 1) {
    if (t < s) red[t] += red[t + s];
    __syncthreads();
  }
  float inv = 1.f / red[0];
  __syncthreads();
  float a = e * inv;
  L[t] = a;
  red[t] = a * qkvb[512 + t];
  __syncthreads();
  for (int s = 128; s > 0; s >>= 1) {
    if (t < s) red[t] += red[t + s];
    __syncthreads();
  }
  if (t == 0) ws[OFF_CV + row] = red[0];
}

// ---------------- const[b,o] = pb[o] + (Pw @ cv[b])[o] ----------------------
__global__ __launch_bounds__(256) void constv_k(const float* __restrict__ pw,
                                                const float* __restrict__ pb,
                                                float* __restrict__ ws) {
  int b = blockIdx.x, t = threadIdx.x;
  __shared__ float cvs[256];
  cvs[t] = ws[OFF_CV + b * 256 + t];
  __syncthreads();
  const float* w = pw + (size_t)t * 256;
  float acc = pb[t];
#pragma unroll 8
  for (int c = 0; c < 256; ++c) acc += w[c] * cvs[c];
  ws[OFF_CONST + b * 256 + t] = acc;
}

// ---------------- final: out = x + S[b] @ xn + const ------------------------
__global__ __launch_bounds__(256) void final_k(const float* __restrict__ x,
                                               float* __restrict__ out,
                                               const float* __restrict__ ws) {
  int b = blockIdx.y;
  int nt = blockIdx.x & 63, mt = blockIdx.x >> 6;
  int m0 = mt * 64, n0 = nt * 64;
  int t = threadIdx.x, tx = t & 15, ty = t >> 4;
  __shared__ __align__(16) float As[32][68], Bs[32][68];
  __shared__ float scS[256], shS[256];
  const float* Sb = ws + OFF_S + (size_t)b * 65536;
  const float* xb = x + (size_t)b * C_ * N_;
  scS[t] = ws[OFF_SC + b * 256 + t];
  shS[t] = ws[OFF_SH + b * 256 + t];
  __syncthreads();
  float acc[4][4] = {};
  for (int k0 = 0; k0 < 256; k0 += 32) {
    {
      int k = t & 31, m = t >> 5;
#pragma unroll
      for (int i = 0; i < 8; ++i)
        As[k][m + i * 8] = Sb[(m0 + m + i * 8) * 256 + k0 + k];
    }
    {
      int j = t & 63, k = t >> 6;
#pragma unroll
      for (int i = 0; i < 8; ++i) {
        int c = k0 + k + i * 4;
        Bs[k + i * 4][j] = xb[(size_t)c * N_ + n0 + j] * scS[c] + shS[c];
      }
    }
    __syncthreads();
#pragma unroll
    for (int kk = 0; kk < 32; ++kk) {
      const float4 a = *(const float4*)&As[kk][ty * 4];
      const float4 bb = *(const float4*)&Bs[kk][tx * 4];
      const float ar[4] = {a.x, a.y, a.z, a.w};
      const float br[4] = {bb.x, bb.y, bb.z, bb.w};
#pragma unroll
      for (int r = 0; r < 4; ++r)
#pragma unroll
        for (int s = 0; s < 4; ++s) acc[r][s] = fmaf(ar[r], br[s], acc[r][s]);
    }
    __syncthreads();
  }
#pragma unroll
  for (int r = 0; r < 4; ++r) {
    int o = m0 + ty * 4 + r;
    float cst = ws[OFF_CONST + b * 256 + o];
    const float4 xv = *(const float4*)&xb[(size_t)o * N_ + n0 + tx * 4];
    float4 ov;
    ov.x = acc[r][0] + xv.x + cst;
    ov.y = acc[r][1] + xv.y + cst;
    ov.z = acc[r][2] + xv.z + cst;
    ov.w = acc[r][3] + xv.w + cst;
    *(float4*)&out[(size_t)b * C_ * N_ + (size_t)o * N_ + n0 + tx * 4] = ov;
  }
}

extern "C" void kernel_launch(void* const* d_in, const int* in_sizes, int n_in,
                              void* d_out, int out_size, void* d_ws,
                              size_t ws_size, hipStream_t stream) {
  const float* x = (const float*)d_in[0];
  const float* gw = (const float*)d_in[1];
  const float* gb = (const float*)d_in[2];
  const float* qkvw = (const float*)d_in[3];
  const float* qkvb = (const float*)d_in[4];
  const float* pw = (const float*)d_in[5];
  const float* pb = (const float*)d_in[6];
  float* out = (float*)d_out;
  float* ws = (float*)d_ws;

  hipLaunchKernelGGL(gn_stats_k, dim3(256), dim3(256), 0, stream, x, gw, gb, ws);
  hipLaunchKernelGGL(rall_k, dim3(32), dim3(256), 0, stream, qkvw, ws);
  hipLaunchKernelGGL(gram_k, dim3(16, 32), dim3(256), 0, stream, x, ws);
  // T1 = Wq @ G
  hipLaunchKernelGGL((sgemm256_k<false, false>), dim3(16, 32), dim3(256), 0,
                     stream, qkvw, (size_t)0, ws + OFF_GM, (size_t)65536,
                     ws + OFF_T1, ws + OFF_RALL, qkvb);
  // logits = T1 @ Wk^T * scale (+ bias corrections)
  hipLaunchKernelGGL((sgemm256_k<true, true>), dim3(16, 32), dim3(256), 0,
                     stream, ws + OFF_T1, (size_t)65536, qkvw + 65536,
                     (size_t)0, ws + OFF_L, ws + OFF_RALL, qkvb);
  hipLaunchKernelGGL(softmax_k, dim3(8192), dim3(256), 0, stream, ws, qkvb);
  // T2 = Pw @ attn
  hipLaunchKernelGGL((sgemm256_k<false, false>), dim3(16, 32), dim3(256), 0,
                     stream, pw, (size_t)0, ws + OFF_L, (size_t)65536,
                     ws + OFF_T2, ws + OFF_RALL, qkvb);
  // S = T2 @ Wv
  hipLaunchKernelGGL((sgemm256_k<false, false>), dim3(16, 32), dim3(256), 0,
                     stream, ws + OFF_T2, (size_t)65536, qkvw + 131072,
                     (size_t)0, ws + OFF_S, ws + OFF_RALL, qkvb);
  hipLaunchKernelGGL(constv_k, dim3(32), dim3(256), 0, stream, pw, pb, ws);
  hipLaunchKernelGGL(final_k, dim3(256, 32), dim3(256), 0, stream, x, out, ws);
}

// Round 2
// 357.868 us; speedup vs baseline: 2.0389x; 2.0389x over previous
//
#include <hip/hip_runtime.h>

// SelfAttention block, algebraically restructured + f16-MFMA for the two
// heavy GEMMs:
//   xn = GN(x) = x*sc[b,c] + sh[b,c]
//   G[b] = xn @ xn^T        (256x256, K=4096)  -- split-f16 MFMA, x read once
//   logits = (Wq G Wk^T + bias corr)*scale     (small fp32 GEMMs, per batch)
//   attn = softmax(logits)
//   S[b] = Pw @ attn @ Wv                      (small fp32)
//   out = x + S[b] @ xn + const[b,o]           (f16 MFMA, K=256)

#define B_ 32
#define C_ 256
#define N_ 4096
#define CPG 32
#define GSIZE (CPG * N_)
#define EPSV 1e-5f
#define SCALE 0.0625f

// workspace layout (float units)
#define OFF_SC    0
#define OFF_SH    8192
#define OFF_SVEC  16384
#define OFF_RALL  24576
#define OFF_CV    49152
#define OFF_CONST 57344
#define OFF_GM    65536
#define OFF_T1    (OFF_GM + 2097152)
#define OFF_L     (OFF_T1 + 2097152)
#define OFF_T2    (OFF_L + 2097152)
#define OFF_S     (OFF_T2 + 2097152)
#define OFF_S16   (OFF_S + 2097152)   // 2M halves = 1M floats

typedef _Float16 half_t;
typedef half_t f16x8 __attribute__((ext_vector_type(8)));
typedef float f32x16 __attribute__((ext_vector_type(16)));

// ---------------- GroupNorm stats: mean/rstd per (b,g) + per-channel sums ----
__global__ __launch_bounds__(256) void gn_stats_k(
    const float* __restrict__ x, const float* __restrict__ gw,
    const float* __restrict__ gb, float* __restrict__ ws) {
  int blk = blockIdx.x, b = blk >> 3, g = blk & 7;
  int t = threadIdx.x, lane = t & 63, wid = t >> 6;
  __shared__ float wsum[4], wsq[4], chs[32], stats[2];
  float gs = 0.f, gq = 0.f;
  const float4* xg = (const float4*)(x + ((size_t)(b * C_) + g * CPG) * N_);
  for (int cc = 0; cc < CPG; ++cc) {
    const float4* p = xg + cc * (N_ / 4);
    float s = 0.f, q = 0.f;
#pragma unroll
    for (int j = 0; j < 4; ++j) {
      float4 v = p[t + j * 256];
      s += v.x + v.y + v.z + v.w;
      q += v.x * v.x + v.y * v.y + v.z * v.z + v.w * v.w;
    }
#pragma unroll
    for (int off = 32; off > 0; off >>= 1) {
      s += __shfl_down(s, off);
      q += __shfl_down(q, off);
    }
    if (lane == 0) { wsum[wid] = s; wsq[wid] = q; }
    __syncthreads();
    if (t == 0) {
      float cs = wsum[0] + wsum[1] + wsum[2] + wsum[3];
      float cq = wsq[0] + wsq[1] + wsq[2] + wsq[3];
      chs[cc] = cs; gs += cs; gq += cq;
    }
    __syncthreads();
  }
  if (t == 0) {
    float mean = gs * (1.f / GSIZE);
    float var = gq * (1.f / GSIZE) - mean * mean;
    stats[0] = mean;
    stats[1] = rsqrtf(var + EPSV);
  }
  __syncthreads();
  if (t < CPG) {
    int c = g * CPG + t, gi = b * C_ + c;
    float scv = stats[1] * gw[c];
    float shv = gb[c] - stats[0] * scv;
    ws[OFF_SC + gi] = scv;
    ws[OFF_SH + gi] = shv;
    ws[OFF_SVEC + gi] = chs[t] * scv + (float)N_ * shv;
  }
}

// ---------------- r_all[b,o] = (Wqkv @ svec)[o], o in [0,768) ----------------
__global__ __launch_bounds__(256) void rall_k(const float* __restrict__ qkvw,
                                              float* __restrict__ ws) {
  int b = blockIdx.x, t = threadIdx.x;
  __shared__ float s[256];
  s[t] = ws[OFF_SVEC + b * C_ + t];
  __syncthreads();
  for (int oo = 0; oo < 3; ++oo) {
    int o = t + oo * 256;
    const float* w = qkvw + (size_t)o * C_;
    float acc = 0.f;
#pragma unroll 8
    for (int c = 0; c < C_; ++c) acc += w[c] * s[c];
    ws[OFF_RALL + b * 768 + o] = acc;
  }
}

// ---------------- Gram via split-f16 MFMA -----------------------------------
// grid: 256 = 32 batches x 8 K-slices (K=512 each). Block: 512 thr, 8 waves.
// LDS tile: [256 rows][256B] per chunk of 64 k: h[64 halves] | l[64 halves],
// XOR-swizzled in 16B slots so frag reads are ~2-way (free).
__global__ __launch_bounds__(512, 1) void gram_mfma_k(
    const float* __restrict__ x, float* __restrict__ ws) {
  __shared__ __align__(16) char hl[65536];
  __shared__ float scs[256], shs[256];
  int b = blockIdx.x >> 3, ks = blockIdx.x & 7;
  int t = threadIdx.x;
  if (t < 256) {
    scs[t] = ws[OFF_SC + b * 256 + t];
    shs[t] = ws[OFF_SH + b * 256 + t];
  }
  __syncthreads();
  const float* xb = x + (size_t)b * (C_ * (size_t)N_) + ks * 512;
  int lane = t & 63, w = t >> 6;
  int wm = w >> 2, wn = w & 3;         // 2x4 wave grid: wave tile 128x64
  int r31 = lane & 31, hi = lane >> 5;

  f32x16 acc[4][2] = {};
  float4 stg[8];

#define GRAM_LOAD(c)                                                     \
  {                                                                      \
    const float* base = xb + (c) * 64;                                   \
    _Pragma("unroll") for (int p = 0; p < 8; ++p) {                      \
      int f = t + p * 512;                                               \
      stg[p] = *(const float4*)(base + (size_t)(f >> 4) * N_ + (f & 15) * 4); \
    }                                                                    \
  }

#define GRAM_WRITE()                                                     \
  {                                                                      \
    _Pragma("unroll") for (int p = 0; p < 8; ++p) {                      \
      int f = t + p * 512;                                               \
      int row = f >> 4, c4 = f & 15;                                     \
      float sc = scs[row], sh = shs[row];                                \
      float v0 = stg[p].x * sc + sh, v1 = stg[p].y * sc + sh;            \
      float v2 = stg[p].z * sc + sh, v3 = stg[p].w * sc + sh;            \
      union { half_t h[4]; uint2 u; } H, L;                              \
      H.h[0] = (half_t)v0; H.h[1] = (half_t)v1;                          \
      H.h[2] = (half_t)v2; H.h[3] = (half_t)v3;                          \
      L.h[0] = (half_t)(v0 - (float)H.h[0]);                            \
      L.h[1] = (half_t)(v1 - (float)H.h[1]);                            \
      L.h[2] = (half_t)(v2 - (float)H.h[2]);                            \
      L.h[3] = (half_t)(v3 - (float)H.h[3]);                            \
      int sw = (row & 15) << 4;                                          \
      char* rp = hl + row * 256;                                         \
      int b16 = (c4 >> 1) << 4, off8 = (c4 & 1) * 8;                     \
      *(uint2*)(rp + (b16 ^ sw) + off8) = H.u;                           \
      *(uint2*)(rp + ((128 + b16) ^ sw) + off8) = L.u;                   \
    }                                                                    \
  }

  GRAM_LOAD(0);
  GRAM_WRITE();
  __syncthreads();
  for (int c = 0; c < 8; ++c) {
    if (c < 7) GRAM_LOAD(c + 1);
    // MFMA over chunk c: 4 k-steps of 16
#pragma unroll
    for (int kk = 0; kk < 4; ++kk) {
      int kb = kk * 32 + hi * 16;
      f16x8 Ah[4], Al[4], Bh[2], Bl[2];
#pragma unroll
      for (int m = 0; m < 4; ++m) {
        int row = wm * 128 + m * 32 + r31;
        char* rp = hl + row * 256;
        int sw = (row & 15) << 4;
        Ah[m] = *(const f16x8*)(rp + (kb ^ sw));
        Al[m] = *(const f16x8*)(rp + ((128 + kb) ^ sw));
      }
#pragma unroll
      for (int n = 0; n < 2; ++n) {
        int row = wn * 64 + n * 32 + r31;
        char* rp = hl + row * 256;
        int sw = (row & 15) << 4;
        Bh[n] = *(const f16x8*)(rp + (kb ^ sw));
        Bl[n] = *(const f16x8*)(rp + ((128 + kb) ^ sw));
      }
#pragma unroll
      for (int m = 0; m < 4; ++m)
#pragma unroll
        for (int n = 0; n < 2; ++n) {
          acc[m][n] = __builtin_amdgcn_mfma_f32_32x32x16_f16(Ah[m], Bh[n], acc[m][n], 0, 0, 0);
          acc[m][n] = __builtin_amdgcn_mfma_f32_32x32x16_f16(Ah[m], Bl[n], acc[m][n], 0, 0, 0);
          acc[m][n] = __builtin_amdgcn_mfma_f32_32x32x16_f16(Al[m], Bh[n], acc[m][n], 0, 0, 0);
        }
    }
    __syncthreads();
    if (c < 7) {
      GRAM_WRITE();
    }
    __syncthreads();
  }
  float* G = ws + OFF_GM + (size_t)b * 65536;
#pragma unroll
  for (int m = 0; m < 4; ++m)
#pragma unroll
    for (int n = 0; n < 2; ++n)
#pragma unroll
      for (int r = 0; r < 16; ++r) {
        int row = wm * 128 + m * 32 + (r & 3) + 8 * (r >> 2) + 4 * hi;
        int col = wn * 64 + n * 32 + r31;
        atomicAdd(G + row * 256 + col, acc[m][n][r]);
      }
}

// ---------------- small GEMM 256x256x256 per batch (fp32) -------------------
template <bool BTRANS, bool LOGITS>
__global__ __launch_bounds__(256) void sgemm256_k(
    const float* __restrict__ A, size_t aBS, const float* __restrict__ Bm,
    size_t bBS, float* __restrict__ Cm, const float* __restrict__ rall,
    const float* __restrict__ qkvb) {
  int b = blockIdx.y;
  int mt = blockIdx.x >> 2, nt = blockIdx.x & 3;
  int m0 = mt * 64, j0 = nt * 64;
  int t = threadIdx.x, tx = t & 15, ty = t >> 4;
  __shared__ __align__(16) float As[32][68], Bs[32][68];
  const float* Ab = A + aBS * b;
  const float* Bb = Bm + bBS * b;
  float acc[4][4] = {};
  for (int k0 = 0; k0 < 256; k0 += 32) {
    {
      int k = t & 31, m = t >> 5;
#pragma unroll
      for (int i = 0; i < 8; ++i)
        As[k][m + i * 8] = Ab[(m0 + m + i * 8) * 256 + k0 + k];
    }
    if (!BTRANS) {
      int j = t & 63, k = t >> 6;
#pragma unroll
      for (int i = 0; i < 8; ++i)
        Bs[k + i * 4][j] = Bb[(k0 + k + i * 4) * 256 + j0 + j];
    } else {
      int k = t & 31, j = t >> 5;
#pragma unroll
      for (int i = 0; i < 8; ++i)
        Bs[k][j + i * 8] = Bb[(j0 + j + i * 8) * 256 + k0 + k];
    }
    __syncthreads();
#pragma unroll
    for (int kk = 0; kk < 32; ++kk) {
      const float4 a = *(const float4*)&As[kk][ty * 4];
      const float4 bb = *(const float4*)&Bs[kk][tx * 4];
      const float ar[4] = {a.x, a.y, a.z, a.w};
      const float br[4] = {bb.x, bb.y, bb.z, bb.w};
#pragma unroll
      for (int r = 0; r < 4; ++r)
#pragma unroll
        for (int s = 0; s < 4; ++s) acc[r][s] = fmaf(ar[r], br[s], acc[r][s]);
    }
    __syncthreads();
  }
#pragma unroll
  for (int r = 0; r < 4; ++r) {
    int i = m0 + ty * 4 + r;
#pragma unroll
    for (int s = 0; s < 4; ++s) {
      int j = j0 + tx * 4 + s;
      float v = acc[r][s];
      if (LOGITS) {
        float bq = qkvb[i], bk = qkvb[256 + j];
        float rq = rall[b * 768 + i], rk = rall[b * 768 + 256 + j];
        v = (v + bq * rk + bk * rq + 4096.f * bq * bk) * SCALE;
      }
      Cm[(size_t)b * 65536 + i * 256 + j] = v;
    }
  }
}

// ---------------- softmax over rows of logits (in place) + cv ---------------
__global__ __launch_bounds__(256) void softmax_k(float* __restrict__ ws,
                                                 const float* __restrict__ qkvb) {
  int row = blockIdx.x;
  int t = threadIdx.x;
  __shared__ float red[256];
  float* L = ws + OFF_L + (size_t)row * 256;
  float v = L[t];
  red[t] = v;
  __syncthreads();
  for (int s = 128; s > 0; s >>= 1) {
    if (t < s) red[t] = fmaxf(red[t], red[t + s]);
    __syncthreads();
  }
  float m = red[0];
  __syncthreads();
  float e = __expf(v - m);
  red[t] = e;
  __syncthreads();
  for (int s = 128; s > 0; s >>= 1) {
    if (t < s) red[t] += red[t + s];
    __syncthreads();
  }
  float inv = 1.f / red[0];
  __syncthreads();
  float a = e * inv;
  L[t] = a;
  red[t] = a * qkvb[512 + t];
  __syncthreads();
  for (int s = 128; s > 0; s >>= 1) {
    if (t < s) red[t] += red[t + s];
    __syncthreads();
  }
  if (t == 0) ws[OFF_CV + row] = red[0];
}

// ---------------- const[b,o] = pb[o] + (Pw @ cv[b])[o] ----------------------
__global__ __launch_bounds__(256) void constv_k(const float* __restrict__ pw,
                                                const float* __restrict__ pb,
                                                float* __restrict__ ws) {
  int b = blockIdx.x, t = threadIdx.x;
  __shared__ float cvs[256];
  cvs[t] = ws[OFF_CV + b * 256 + t];
  __syncthreads();
  const float* w = pw + (size_t)t * 256;
  float acc = pb[t];
#pragma unroll 8
  for (int c = 0; c < 256; ++c) acc += w[c] * cvs[c];
  ws[OFF_CONST + b * 256 + t] = acc;
}

// ---------------- S fp32 -> f16 copy ----------------------------------------
__global__ __launch_bounds__(256) void sconv_k(float* __restrict__ ws) {
  size_t i = (size_t)blockIdx.x * 256 + threadIdx.x;  // float4 index
  float4 v = *(const float4*)(ws + OFF_S + i * 4);
  union { half_t h[4]; uint2 u; } p;
  p.h[0] = (half_t)v.x; p.h[1] = (half_t)v.y;
  p.h[2] = (half_t)v.z; p.h[3] = (half_t)v.w;
  *(uint2*)((half_t*)(ws + OFF_S16) + i * 4) = p.u;
}

// ---------------- final: out = x + S[b] @ xn + const, f16 MFMA --------------
// grid (64 n-tiles, 32 b); block 256 thr = 4 waves; wave tile 64o x 64n.
// A (=S f16) read direct from global (L2-resident); B (=xn^T) staged via LDS.
__global__ __launch_bounds__(256, 3) void final_mfma_k(
    const float* __restrict__ x, float* __restrict__ out,
    const float* __restrict__ ws) {
  __shared__ __align__(16) char Bt[16384];  // [64 n][256B = 128 c halves] swizzled
  int b = blockIdx.y, n0 = blockIdx.x * 64;
  int t = threadIdx.x, lane = t & 63, w = t >> 6;
  int r31 = lane & 31, hi = lane >> 5;
  const half_t* Shb = (const half_t*)(ws + OFF_S16) + (size_t)b * 65536;
  const float* xb = x + (size_t)b * (C_ * (size_t)N_);
  const float* scb = ws + OFF_SC + b * 256;
  const float* shb = ws + OFF_SH + b * 256;
  f32x16 acc[2][2] = {};
  for (int c0 = 0; c0 < 256; c0 += 128) {
    // stage xn^T chunk: rows n (64), cols c (128)
#pragma unroll
    for (int p = 0; p < 8; ++p) {
      int f = t + p * 256;
      int cl = f >> 4, j4 = f & 15;
      int c = c0 + cl;
      float4 v = *(const float4*)(xb + (size_t)c * N_ + n0 + j4 * 4);
      float sc = scb[c], sh = shb[c];
      float vv[4] = {v.x * sc + sh, v.y * sc + sh, v.z * sc + sh, v.w * sc + sh};
      int cb = cl * 2, b16 = cb & ~15, off = cb & 15;
#pragma unroll
      for (int e = 0; e < 4; ++e) {
        int nn = j4 * 4 + e;
        *(half_t*)(Bt + nn * 256 + (b16 ^ ((nn & 15) << 4)) + off) = (half_t)vv[e];
      }
    }
    __syncthreads();
#pragma unroll
    for (int kk = 0; kk < 8; ++kk) {
      int byte = kk * 32 + hi * 16;
      int cA = c0 + kk * 16 + hi * 8;
      f16x8 Af[2], Bf[2];
#pragma unroll
      for (int m = 0; m < 2; ++m) {
        int o = w * 64 + m * 32 + r31;
        Af[m] = *(const f16x8*)(Shb + (size_t)o * 256 + cA);
      }
#pragma unroll
      for (int n = 0; n < 2; ++n) {
        int nn = n * 32 + r31;
        Bf[n] = *(const f16x8*)(Bt + nn * 256 + (byte ^ ((nn & 15) << 4)));
      }
#pragma unroll
      for (int m = 0; m < 2; ++m)
#pragma unroll
        for (int n = 0; n < 2; ++n)
          acc[m][n] = __builtin_amdgcn_mfma_f32_32x32x16_f16(Af[m], Bf[n], acc[m][n], 0, 0, 0);
    }
    __syncthreads();
  }
  float* ob = out + (size_t)b * (C_ * (size_t)N_);
  const float* cstb = ws + OFF_CONST + b * 256;
#pragma unroll
  for (int m = 0; m < 2; ++m)
#pragma unroll
    for (int r = 0; r < 16; ++r) {
      int o = w * 64 + m * 32 + (r & 3) + 8 * (r >> 2) + 4 * hi;
      float cv = cstb[o];
      size_t base = (size_t)o * N_ + n0;
#pragma unroll
      for (int n = 0; n < 2; ++n) {
        int col = n * 32 + r31;
        ob[base + col] = acc[m][n][r] + xb[base + col] + cv;
      }
    }
}

extern "C" void kernel_launch(void* const* d_in, const int* in_sizes, int n_in,
                              void* d_out, int out_size, void* d_ws,
                              size_t ws_size, hipStream_t stream) {
  const float* x = (const float*)d_in[0];
  const float* gw = (const float*)d_in[1];
  const float* gb = (const float*)d_in[2];
  const float* qkvw = (const float*)d_in[3];
  const float* qkvb = (const float*)d_in[4];
  const float* pw = (const float*)d_in[5];
  const float* pb = (const float*)d_in[6];
  float* out = (float*)d_out;
  float* ws = (float*)d_ws;

  // zero G (gram accumulates atomically; must re-zero every replay)
  hipMemsetAsync(ws + OFF_GM, 0, (size_t)32 * 65536 * 4, stream);
  hipLaunchKernelGGL(gn_stats_k, dim3(256), dim3(256), 0, stream, x, gw, gb, ws);
  hipLaunchKernelGGL(rall_k, dim3(32), dim3(256), 0, stream, qkvw, ws);
  hipLaunchKernelGGL(gram_mfma_k, dim3(256), dim3(512), 0, stream, x, ws);
  // T1 = Wq @ G
  hipLaunchKernelGGL((sgemm256_k<false, false>), dim3(16, 32), dim3(256), 0,
                     stream, qkvw, (size_t)0, ws + OFF_GM, (size_t)65536,
                     ws + OFF_T1, ws + OFF_RALL, qkvb);
  // logits = T1 @ Wk^T * scale (+ bias corrections)
  hipLaunchKernelGGL((sgemm256_k<true, true>), dim3(16, 32), dim3(256), 0,
                     stream, ws + OFF_T1, (size_t)65536, qkvw + 65536,
                     (size_t)0, ws + OFF_L, ws + OFF_RALL, qkvb);
  hipLaunchKernelGGL(softmax_k, dim3(8192), dim3(256), 0, stream, ws, qkvb);
  // T2 = Pw @ attn
  hipLaunchKernelGGL((sgemm256_k<false, false>), dim3(16, 32), dim3(256), 0,
                     stream, pw, (size_t)0, ws + OFF_L, (size_t)65536,
                     ws + OFF_T2, ws + OFF_RALL, qkvb);
  // S = T2 @ Wv
  hipLaunchKernelGGL((sgemm256_k<false, false>), dim3(16, 32), dim3(256), 0,
                     stream, ws + OFF_T2, (size_t)65536, qkvw + 131072,
                     (size_t)0, ws + OFF_S, ws + OFF_RALL, qkvb);
  hipLaunchKernelGGL(sconv_k, dim3(2048), dim3(256), 0, stream, ws);
  hipLaunchKernelGGL(constv_k, dim3(32), dim3(256), 0, stream, pw, pb, ws);
  hipLaunchKernelGGL(final_mfma_k, dim3(64, 32), dim3(256), 0, stream, x, out, ws);
}